// Round 1
// baseline (1046.850 us; speedup 1.0000x reference)
//
#include <hip/hip_runtime.h>
#include <hip/hip_bf16.h>
#include <stdint.h>

// ---------------------------------------------------------------------------
// GnnCritic fused forward, MI355X (gfx950).
//
// q{1,2}[b] = sum_n relu(relu(inp[n,b] @ W1 + b1) @ W2 + b2) @ wr + br
// inp[n,b]  = [obs_body(10) | obs_obj_n(15) | segmax_n(edge_features)(128)]
//
// Strategy: split-bf16 MFMA (hi/lo, 3-term: ah*bh + al*bh + ah*bl) for
// fp32-class accuracy (~1e-5 rel) at bf16 matrix-core rate. Fully fused:
// one block owns 64 batch rows, loops 3 objects x 2 nets, readout fused
// into the L2 epilogue (sum over objects commutes with the final linear).
// Weights pre-packed into MFMA B-fragment order (hi/lo) in d_ws by a prep
// kernel each launch (d_ws is re-poisoned before every timed call).
// ---------------------------------------------------------------------------

#define B_TOT 65536
#define MB 64

typedef __bf16 bf16x8 __attribute__((ext_vector_type(8)));
typedef float f32x4 __attribute__((ext_vector_type(4)));
typedef unsigned short u16x8 __attribute__((ext_vector_type(8)));

// packed-weight offsets in d_ws, in ushort units (each frag = 64 lanes x 8 bf16)
#define OFF_W1H 0        // 80 frags  (K=160: kf 0..4, 16 cfg)
#define OFF_W1L 40960
#define OFF_W2H 81920    // 128 frags (K=256: kf 0..7)
#define OFF_W2L 147456
#define OFF_W3H 212992
#define OFF_W3L 253952
#define OFF_W4H 294912
#define OFF_W4L 360448   // end = 425984 ushorts = 832 KB

__device__ inline unsigned short f2bf(float f) {  // round-to-nearest-even
  unsigned int u = __float_as_uint(f);
  u += 0x7fffu + ((u >> 16) & 1u);
  return (unsigned short)(u >> 16);
}
__device__ inline float bf2f(unsigned short h) {
  return __uint_as_float(((unsigned int)h) << 16);
}
__device__ inline void split2(float v, unsigned short& h, unsigned short& l) {
  h = f2bf(v);
  l = f2bf(v - bf2f(h));
}

// ---------------------------------------------------------------------------
// Prep: pack W (Kreal x 256 row-major fp32) into B-fragment order, hi/lo bf16.
// Fragment (kf,cfg): lane L, elem j holds W[kf*32 + (L>>4)*8 + j][cfg*16 + (L&15)].
// One 64-thread block per fragment; 80+128+80+128 = 416 blocks.
// ---------------------------------------------------------------------------
__global__ void prep_weights(const float* __restrict__ w1, const float* __restrict__ w2,
                             const float* __restrict__ w3, const float* __restrict__ w4,
                             unsigned short* __restrict__ ws) {
  int bid = blockIdx.x;
  int lane = threadIdx.x;
  const float* w; int f, Kreal; unsigned short *oh, *ol;
  if (bid < 80)       { w = w1; f = bid;       Kreal = 153; oh = ws + OFF_W1H; ol = ws + OFF_W1L; }
  else if (bid < 208) { w = w2; f = bid - 80;  Kreal = 256; oh = ws + OFF_W2H; ol = ws + OFF_W2L; }
  else if (bid < 288) { w = w3; f = bid - 208; Kreal = 153; oh = ws + OFF_W3H; ol = ws + OFF_W3L; }
  else                { w = w4; f = bid - 288; Kreal = 256; oh = ws + OFF_W4H; ol = ws + OFF_W4L; }
  int kf = f >> 4, cfg = f & 15;
  int c  = cfg * 16 + (lane & 15);
  int kb = kf * 32 + (lane >> 4) * 8;
  u16x8 H, L;
#pragma unroll
  for (int j = 0; j < 8; ++j) {
    int k = kb + j;
    float v = (k < Kreal) ? w[k * 256 + c] : 0.f;
    unsigned short h, l; split2(v, h, l);
    H[j] = h; L[j] = l;
  }
  size_t idx = ((size_t)f * 64 + lane) * 8;
  *(u16x8*)(oh + idx) = H;
  *(u16x8*)(ol + idx) = L;
}

// ---------------------------------------------------------------------------
// Main fused kernel helpers
// ---------------------------------------------------------------------------
__device__ inline void zero_acc(f32x4 acc[4][2]) {
#pragma unroll
  for (int rf = 0; rf < 4; ++rf)
#pragma unroll
    for (int cf = 0; cf < 2; ++cf)
      acc[rf][cf] = (f32x4){0.f, 0.f, 0.f, 0.f};
}

// GEMM over one staged A-tile (64 x 32*KF, hi/lo in LDS) against packed W.
// Wave owns 32 output cols (cfg = wave*2 + cf). acc[rf][cf]: D rows rf*16 +
// (lane>>4)*4 + i, col = wave*32 + cf*16 + (lane&15).
template<int KF, int ASTRIDE>
__device__ inline void gemm_phase(const unsigned short* Ah, const unsigned short* Al,
                                  const unsigned short* wH, const unsigned short* wL,
                                  int lane, int wave, f32x4 acc[4][2]) {
  const int arow = lane & 15;
  const int kgr  = (lane >> 4) * 8;
#pragma unroll
  for (int kf = 0; kf < KF; ++kf) {
    bf16x8 ah[4], al[4];
#pragma unroll
    for (int rf = 0; rf < 4; ++rf) {
      ah[rf] = *(const bf16x8*)(Ah + (rf * 16 + arow) * ASTRIDE + kf * 32 + kgr);
      al[rf] = *(const bf16x8*)(Al + (rf * 16 + arow) * ASTRIDE + kf * 32 + kgr);
    }
#pragma unroll
    for (int cf = 0; cf < 2; ++cf) {
      const size_t fidx = ((size_t)(kf * 16 + wave * 2 + cf) * 64 + lane) * 8;
      bf16x8 bh = *(const bf16x8*)(wH + fidx);
      bf16x8 bl = *(const bf16x8*)(wL + fidx);
#pragma unroll
      for (int rf = 0; rf < 4; ++rf) {
        acc[rf][cf] = __builtin_amdgcn_mfma_f32_16x16x32_bf16(ah[rf], bh, acc[rf][cf], 0, 0, 0);
        acc[rf][cf] = __builtin_amdgcn_mfma_f32_16x16x32_bf16(al[rf], bh, acc[rf][cf], 0, 0, 0);
        acc[rf][cf] = __builtin_amdgcn_mfma_f32_16x16x32_bf16(ah[rf], bl, acc[rf][cf], 0, 0, 0);
      }
    }
  }
}

__device__ inline void store_hidden(f32x4 acc[4][2], const float* bias, int lane, int wave,
                                    unsigned short (*Hh)[264], unsigned short (*Hl)[264]) {
  const int col0 = wave * 32 + (lane & 15);
  const int row0 = (lane >> 4) << 2;
#pragma unroll
  for (int rf = 0; rf < 4; ++rf)
#pragma unroll
    for (int cf = 0; cf < 2; ++cf) {
      int col = col0 + cf * 16;
      float bv = bias[col];
#pragma unroll
      for (int i = 0; i < 4; ++i) {
        int row = rf * 16 + row0 + i;
        float h = fmaxf(acc[rf][cf][i] + bv, 0.f);
        unsigned short hh, hl; split2(h, hh, hl);
        Hh[row][col] = hh; Hl[row][col] = hl;
      }
    }
}

__device__ inline void accum_q(f32x4 acc[4][2], const float* bias, const float* wr,
                               int lane, int wave, float qp[4][4]) {
  const int col0 = wave * 32 + (lane & 15);
#pragma unroll
  for (int rf = 0; rf < 4; ++rf)
#pragma unroll
    for (int cf = 0; cf < 2; ++cf) {
      int col = col0 + cf * 16;
      float bv = bias[col];
      float wv = wr[col];
#pragma unroll
      for (int i = 0; i < 4; ++i) {
        float x = fmaxf(acc[rf][cf][i] + bv, 0.f);
        qp[rf][i] += x * wv;
      }
    }
}

// ---------------------------------------------------------------------------
// Main kernel: 512 threads (8 waves), 64 batch rows per block, grid = 1024.
// LDS 118 KB -> 1 block/CU, 2 waves/SIMD.
// ---------------------------------------------------------------------------
__global__ __launch_bounds__(512, 2) void gnn_fused(
    const float* __restrict__ obs, const float* __restrict__ ef, const int* __restrict__ eto,
    const unsigned short* __restrict__ ws,
    const float* __restrict__ b1, const float* __restrict__ b2,
    const float* __restrict__ b3, const float* __restrict__ b4,
    const float* __restrict__ wr1, const float* __restrict__ br1,
    const float* __restrict__ wr2, const float* __restrict__ br2,
    float* __restrict__ out) {
  // strides 168/264: keep 16B alignment for ds_read_b128; ~2-way banks (free)
  __shared__ unsigned short A1h[64][168];
  __shared__ unsigned short A1l[64][168];
  __shared__ unsigned short A2h[64][264];
  __shared__ unsigned short A2l[64][264];
  __shared__ float sbias[4][256];
  __shared__ float swr[2][256];
  __shared__ float qbuf[2][8][64];

  const int tid  = threadIdx.x;
  const int lane = tid & 63;
  const int wave = tid >> 6;
  const int b0   = blockIdx.x * MB;

  if (tid < 256) {
    sbias[0][tid] = b1[tid]; sbias[1][tid] = b2[tid];
    sbias[2][tid] = b3[tid]; sbias[3][tid] = b4[tid];
    swr[0][tid]   = wr1[tid]; swr[1][tid]  = wr2[tid];
  }
  int e2s[6];
#pragma unroll
  for (int e = 0; e < 6; ++e) e2s[e] = eto[e];

  float qp1[4][4] = {};
  float qp2[4][4] = {};

  for (int n = 0; n < 3; ++n) {
    // ---- build A1 = [body | obj_n | segmax_n(ef)] as hi/lo bf16 ----------
    // (no barrier needed before build: it only writes A1, whose last readers
    //  were barrier-separated already; overlaps prev object's L2 MFMAs)
    for (int idx = tid; idx < 64 * 32; idx += 512) {   // cols 0..24
      int r = idx >> 5, k = idx & 31;
      if (k < 25) {
        int b = b0 + r;
        float v = (k < 10) ? obs[b * 55 + k] : obs[b * 55 + 10 + n * 15 + (k - 10)];
        unsigned short h, l; split2(v, h, l);
        A1h[r][k] = h; A1l[r][k] = l;
      }
    }
    for (int idx = tid; idx < 64 * 16; idx += 512) {   // zero pad 153..167
      int r = idx >> 4, k = 153 + (idx & 15);
      if (k < 168) { A1h[r][k] = 0; A1l[r][k] = 0; }
    }
#pragma unroll
    for (int it = 0; it < 4; ++it) {                   // segmax, cols 25..152
      int job = tid + it * 512;                        // 64 rows x 32 float4
      int r = job >> 5, dq = job & 31;
      size_t b = (size_t)(b0 + r);
      float m0 = -3.0e38f, m1 = m0, m2 = m0, m3 = m0;
#pragma unroll
      for (int e = 0; e < 6; ++e) {
        if (e2s[e] == n) {
          const float4 v = *(const float4*)(ef + (b * 6 + e) * 128 + dq * 4);
          m0 = fmaxf(m0, v.x); m1 = fmaxf(m1, v.y);
          m2 = fmaxf(m2, v.z); m3 = fmaxf(m3, v.w);
        }
      }
      int c = 25 + dq * 4;
      unsigned short h, l;
      split2(m0, h, l); A1h[r][c + 0] = h; A1l[r][c + 0] = l;
      split2(m1, h, l); A1h[r][c + 1] = h; A1l[r][c + 1] = l;
      split2(m2, h, l); A1h[r][c + 2] = h; A1l[r][c + 2] = l;
      split2(m3, h, l); A1h[r][c + 3] = h; A1l[r][c + 3] = l;
    }
    __syncthreads();

    { // net1 layer1 -> hidden
      f32x4 acc[4][2]; zero_acc(acc);
      gemm_phase<5, 168>(&A1h[0][0], &A1l[0][0], ws + OFF_W1H, ws + OFF_W1L, lane, wave, acc);
      store_hidden(acc, sbias[0], lane, wave, A2h, A2l);
    }
    __syncthreads();
    { // net1 layer2 -> q1 partials
      f32x4 acc[4][2]; zero_acc(acc);
      gemm_phase<8, 264>(&A2h[0][0], &A2l[0][0], ws + OFF_W2H, ws + OFF_W2L, lane, wave, acc);
      accum_q(acc, sbias[1], swr[0], lane, wave, qp1);
    }
    __syncthreads();
    { // net2 layer1
      f32x4 acc[4][2]; zero_acc(acc);
      gemm_phase<5, 168>(&A1h[0][0], &A1l[0][0], ws + OFF_W3H, ws + OFF_W3L, lane, wave, acc);
      store_hidden(acc, sbias[2], lane, wave, A2h, A2l);
    }
    __syncthreads();
    { // net2 layer2 -> q2 partials
      f32x4 acc[4][2]; zero_acc(acc);
      gemm_phase<8, 264>(&A2h[0][0], &A2l[0][0], ws + OFF_W4H, ws + OFF_W4L, lane, wave, acc);
      accum_q(acc, sbias[3], swr[1], lane, wave, qp2);
    }
  }

  // ---- readout reduce: sum q-partials over the 16 col-lanes, then waves ----
#pragma unroll
  for (int rf = 0; rf < 4; ++rf)
#pragma unroll
    for (int i = 0; i < 4; ++i) {
      float v1 = qp1[rf][i], v2 = qp2[rf][i];
#pragma unroll
      for (int m = 1; m < 16; m <<= 1) {
        v1 += __shfl_xor(v1, m);
        v2 += __shfl_xor(v2, m);
      }
      if ((lane & 15) == 0) {
        int row = rf * 16 + ((lane >> 4) << 2) + i;
        qbuf[0][wave][row] = v1;
        qbuf[1][wave][row] = v2;
      }
    }
  __syncthreads();
  if (tid < 128) {
    int net = tid >> 6, row = tid & 63;
    float s = 0.f;
#pragma unroll
    for (int w = 0; w < 8; ++w) s += qbuf[net][w][row];
    s += net ? br2[0] : br1[0];
    out[net * B_TOT + b0 + row] = s;
  }
}

// ---------------------------------------------------------------------------
extern "C" void kernel_launch(void* const* d_in, const int* in_sizes, int n_in,
                              void* d_out, int out_size, void* d_ws, size_t ws_size,
                              hipStream_t stream) {
  (void)in_sizes; (void)n_in; (void)out_size; (void)ws_size;
  const float* obs = (const float*)d_in[0];
  // d_in[1] (act) is unused by the reference.
  const float* ef  = (const float*)d_in[2];
  const int*   eto = (const int*)d_in[3];
  const float* w1  = (const float*)d_in[4];  const float* b1  = (const float*)d_in[5];
  const float* w2  = (const float*)d_in[6];  const float* b2  = (const float*)d_in[7];
  const float* w3  = (const float*)d_in[8];  const float* b3  = (const float*)d_in[9];
  const float* w4  = (const float*)d_in[10]; const float* b4  = (const float*)d_in[11];
  const float* wr1 = (const float*)d_in[12]; const float* br1 = (const float*)d_in[13];
  const float* wr2 = (const float*)d_in[14]; const float* br2 = (const float*)d_in[15];
  float* out = (float*)d_out;
  unsigned short* ws = (unsigned short*)d_ws;  // needs 832 KB

  prep_weights<<<416, 64, 0, stream>>>(w1, w2, w3, w4, ws);
  gnn_fused<<<B_TOT / MB, 512, 0, stream>>>(obs, ef, eto, ws,
                                            b1, b2, b3, b4, wr1, br1, wr2, br2, out);
}